// Round 1
// 167.363 us; speedup vs baseline: 1.1889x; 1.1889x over previous
//
#include <hip/hip_runtime.h>

// RelationGAT fused flash-attention, MFMA fp16 (gfx950) -- R8 "no-staging" rewrite.
// out = softmax((x@Wq^T+bq) @ (nb@Wk^T+bk)^T) @ nb @ Wv^T + bv
// bk cancels in softmax. Q~ = x@G + u, G = Wq^T Wk, u = bq^T Wk; K=V=raw nb.
//
// R8 theory: prior kernel was stall-bound (MfmaUtil 13%, VALUBusy 27%, occ 24%):
// per-block LDS staging of L2-resident K/V (256KB) + 2 barriers/stage lock-stepped
// the ~3 waves/SIMD. Fix (learn_hip common-mistake #7): pre-convert nb to fp16 ONCE
// in a prep kernel (permuted Kp[1024][72] + d-major VTp[64][1040]) and read MFMA
// fragments straight from L2. Main kernel: ZERO __syncthreads, LDS only the 17KB
// per-wave Q-transpose slice, defer-max softmax (THR=8, exact math) skips the
// acc-rescale chain on most tiles.
//
// Workspace layout (needs ~300KB):
//   [0,9216)        Gh   fp16 [64][72]   G^T hi
//   [9216,18432)    Gl   fp16 [64][72]   G^T lo
//   [18432,18688)   uW   f32  [64]
//   [18688,166144)  Kp   fp16 [1024][72] rows permuted within 32-groups
//   [166144,299264) VTp  fp16 [64][1040] d-major transpose of nb

#define N_ROWS 100000
#define VT_STRIDE 1040

typedef __attribute__((ext_vector_type(8))) _Float16 half8;
typedef __attribute__((ext_vector_type(4))) float    f32x4;

#define MFMA16(a,b,c) __builtin_amdgcn_mfma_f32_16x16x32_f16((a),(b),(c),0,0,0)

static __device__ __forceinline__ f32x4 zero4() {
    f32x4 v = {0.f, 0.f, 0.f, 0.f};
    return v;
}

// ---------------- prep: G^T hi/lo + u (block 0), nb -> Kp/VTp fp16 (blocks 1..16) ----------------
__global__ __launch_bounds__(256)
void prep_kernel(const float* __restrict__ nb, const float* __restrict__ Wq,
                 const float* __restrict__ bq, const float* __restrict__ Wk,
                 unsigned short* __restrict__ Gh, unsigned short* __restrict__ Gl,
                 float* __restrict__ uW, unsigned short* __restrict__ Kp,
                 unsigned short* __restrict__ VTp)
{
    __shared__ __align__(16) float sm[8192];   // 32KB: blk0 Wk|Wq, blks>0 transpose tile
    const int tid = threadIdx.x;
    if (blockIdx.x == 0) {
        const float4* wk4 = (const float4*)Wk;
        const float4* wq4 = (const float4*)Wq;
        float4* dk = (float4*)sm;
        float4* dq = (float4*)(sm + 4096);
        #pragma unroll
        for (int u = 0; u < 4; u++) {
            dk[u * 256 + tid] = wk4[u * 256 + tid];
            dq[u * 256 + tid] = wq4[u * 256 + tid];
        }
        __syncthreads();
        const int e2 = tid & 63, e1g = (tid >> 6) * 16;
        float g[16];
        #pragma unroll
        for (int q = 0; q < 16; q++) g[q] = 0.f;
        for (int w = 0; w < 64; w++) {
            float kv = sm[w * 64 + e2];
            const float* wqp = sm + 4096 + w * 64 + e1g;
            #pragma unroll
            for (int q = 0; q < 16; q++) g[q] = fmaf(wqp[q], kv, g[q]);
        }
        union { half8 h; uint4 u; } ph0, pl0, ph1, pl1;
        #pragma unroll
        for (int i = 0; i < 8; i++) {
            _Float16 h0 = (_Float16)g[i];
            ph0.h[i] = h0; pl0.h[i] = (_Float16)(g[i] - (float)h0);
            _Float16 h1 = (_Float16)g[8 + i];
            ph1.h[i] = h1; pl1.h[i] = (_Float16)(g[8 + i] - (float)h1);
        }
        *(uint4*)(Gh + e2 * 72 + e1g)     = ph0.u;
        *(uint4*)(Gh + e2 * 72 + e1g + 8) = ph1.u;
        *(uint4*)(Gl + e2 * 72 + e1g)     = pl0.u;
        *(uint4*)(Gl + e2 * 72 + e1g + 8) = pl1.u;
        if (tid < 64) {
            float uu = 0.f;
            for (int w = 0; w < 64; w++) uu = fmaf(bq[w], sm[w * 64 + tid], uu);
            uW[tid] = uu;
        }
    } else {
        const int j0 = (blockIdx.x - 1) * 64;    // this block's 64 keys
        const int jr = tid >> 2;                 // 0..63 local key row
        const int c0 = (tid & 3) * 16;           // 16-elem d chunk
        const float* np = nb + (size_t)(j0 + jr) * 64 + c0;
        float a[16];
        #pragma unroll
        for (int u = 0; u < 4; u++) *(float4*)(a + 4 * u) = *(const float4*)(np + 4 * u);
        // Kp: physical row permutation within 32-group: j=[Q1 Q0 t r1 r0] -> p=[t Q1 Q0 r1 r0]
        const int pr = (jr & ~31) | (((jr >> 2) & 1) << 4) | (((jr >> 3) & 3) << 2) | (jr & 3);
        union { half8 h; uint4 u; } pk0, pk1;
        #pragma unroll
        for (int i = 0; i < 8; i++) { pk0.h[i] = (_Float16)a[i]; pk1.h[i] = (_Float16)a[8 + i]; }
        *(uint4*)(Kp + (size_t)(j0 + pr) * 72 + c0)     = pk0.u;
        *(uint4*)(Kp + (size_t)(j0 + pr) * 72 + c0 + 8) = pk1.u;
        // VTp: transpose via LDS [64][65] f32 (65: conflict-free column reads)
        #pragma unroll
        for (int i = 0; i < 16; i++) sm[jr * 65 + c0 + i] = a[i];
        __syncthreads();
        const int d   = tid >> 2;
        const int jc0 = (tid & 3) * 16;
        union { half8 h; uint4 u; } pv0, pv1;
        #pragma unroll
        for (int i = 0; i < 8; i++) {
            pv0.h[i] = (_Float16)sm[(jc0 + i) * 65 + d];
            pv1.h[i] = (_Float16)sm[(jc0 + 8 + i) * 65 + d];
        }
        *(uint4*)(VTp + (size_t)d * VT_STRIDE + j0 + jc0)     = pv0.u;
        *(uint4*)(VTp + (size_t)d * VT_STRIDE + j0 + jc0 + 8) = pv1.u;
    }
}

// ---------------- main: barrier-free flash loop, K/V frags straight from L2 ----------------
__global__ __launch_bounds__(256, 3)
void attn_kernel(const float* __restrict__ x,
                 const unsigned short* __restrict__ Gh,
                 const unsigned short* __restrict__ Gl,
                 const float* __restrict__ uW,
                 const unsigned short* __restrict__ Kp,
                 const unsigned short* __restrict__ VTp,
                 const float* __restrict__ Wv,
                 const float* __restrict__ bv,
                 float* __restrict__ out)
{
    __shared__ __align__(16) float slices[4 * 1088];   // per-wave [16][68] f32 Q-transpose slice
    const int tid  = threadIdx.x;
    const int lane = tid & 63;
    const int wv   = tid >> 6;     // wave 0..3
    const int Q    = lane >> 4;    // quad 0..3
    const int c    = lane & 15;    // col 0..15
    const int rbase = blockIdx.x * 128 + wv * 32;   // this wave's 32 q-rows
    float* slice = slices + wv * 1088;

    // ------- setup: Q~^T = G^T x^T via MFMA (G from L2) -> q-frags hi/lo -------
    half8 qh[2][2], ql[2][2];   // [rt][ks] -- static indices ONLY
    #pragma unroll
    for (int rt = 0; rt < 2; rt++) {
        int row = rbase + rt * 16 + c;
        if (row > N_ROWS - 1) row = N_ROWS - 1;
        half8 xh[2], xl[2];
        #pragma unroll
        for (int ks = 0; ks < 2; ks++) {
            const float* xp = x + (size_t)row * 64 + ks * 32 + Q * 8;
            float a[8];
            *(float4*)a       = *(const float4*)xp;
            *(float4*)(a + 4) = *(const float4*)(xp + 4);
            #pragma unroll
            for (int i = 0; i < 8; i++) {
                _Float16 h = (_Float16)a[i];
                xh[ks][i] = h;
                xl[ks][i] = (_Float16)(a[i] - (float)h);
            }
        }
        #pragma unroll
        for (int mt = 0; mt < 4; mt++) {
            f32x4 Cm = zero4();
            #pragma unroll
            for (int ks = 0; ks < 2; ks++) {
                half8 gh = *(const half8*)(Gh + (mt * 16 + c) * 72 + ks * 32 + Q * 8);
                half8 gl = *(const half8*)(Gl + (mt * 16 + c) * 72 + ks * 32 + Q * 8);
                Cm = MFMA16(gh, xh[ks], Cm);   // D[dout][x-row]
                Cm = MFMA16(gh, xl[ks], Cm);
                Cm = MFMA16(gl, xh[ks], Cm);
            }
            // C row = dout mt*16+4Q+r, col = x-row c -> slice[x-row][dout]
            *(f32x4*)(slice + c * 68 + mt * 16 + 4 * Q) = Cm;
        }
        __builtin_amdgcn_s_waitcnt(0);   // wave-local LDS RAW
        #pragma unroll
        for (int ks = 0; ks < 2; ks++) {
            const float* qp = slice + c * 68 + ks * 32 + Q * 8;
            const float* up = uW + ks * 32 + Q * 8;
            #pragma unroll
            for (int i = 0; i < 8; i++) {
                float val = qp[i] + up[i];
                _Float16 h = (_Float16)val;
                qh[rt][ks][i] = h;
                ql[rt][ks][i] = (_Float16)(val - (float)h);
            }
        }
        __builtin_amdgcn_s_waitcnt(0);   // reads done before rt=1 overwrites slice
    }
    // slice is wave-private -> NO __syncthreads anywhere; waves free-run.

    // ---------------- flash loop over all 1024 keys, 32 per iteration ----------------
    f32x4 acc[2][4];   // [qt][dt] agg^T C-frags (static idx only)
    #pragma unroll
    for (int qt = 0; qt < 2; qt++)
        #pragma unroll
        for (int dt = 0; dt < 4; dt++) acc[qt][dt] = zero4();
    float mrow[2] = { -3.0e38f, -3.0e38f };
    float lrow[2] = { 0.f, 0.f };

    #pragma unroll 2
    for (int jc = 0; jc < 32; jc++) {
        const int jb = jc * 32;
        // K frags from L2 (Kp pre-permuted: physical rows jb+16t+c are contiguous)
        half8 k0[2], k1[2];
        #pragma unroll
        for (int t = 0; t < 2; t++) {
            const unsigned short* kp = Kp + (size_t)(jb + 16 * t + c) * 72;
            k0[t] = *(const half8*)(kp + Q * 8);
            k1[t] = *(const half8*)(kp + 32 + Q * 8);
        }
        // V frags from L2, hoisted early for latency overlap with QK^T
        half8 vA[4];
        #pragma unroll
        for (int dt = 0; dt < 4; dt++)
            vA[dt] = *(const half8*)(VTp + (size_t)(dt * 16 + c) * VT_STRIDE + jb + Q * 8);

        // S tiles; logical j of S-frag lane(Q,c) reg r = jb + 8Q + 4t + r
        f32x4 S[2][2];   // [t][qt]
        #pragma unroll
        for (int t = 0; t < 2; t++) {
            #pragma unroll
            for (int qt = 0; qt < 2; qt++) {
                f32x4 s = MFMA16(k0[t], qh[qt][0], zero4());
                s = MFMA16(k1[t], qh[qt][1], s);
                s = MFMA16(k0[t], ql[qt][0], s);
                s = MFMA16(k1[t], ql[qt][1], s);
                S[t][qt] = s;
            }
        }
        half8 pB[2];
        #pragma unroll
        for (int qt = 0; qt < 2; qt++) {
            float cm = fmaxf(fmaxf(fmaxf(S[0][qt][0], S[0][qt][1]),
                                   fmaxf(S[0][qt][2], S[0][qt][3])),
                             fmaxf(fmaxf(S[1][qt][0], S[1][qt][1]),
                                   fmaxf(S[1][qt][2], S[1][qt][3])));
            cm = fmaxf(cm, __shfl_xor(cm, 16));
            cm = fmaxf(cm, __shfl_xor(cm, 32));
            // defer-max (T13): only rescale when tile max beats running max by >8.
            // Math is exact; p bounded by e^8 ~ 2981, fine in fp16.
            if (__any(cm > mrow[qt] + 8.f)) {
                const float mn = fmaxf(mrow[qt], cm);
                const float sc = __expf(mrow[qt] - mn);
                mrow[qt] = mn;
                lrow[qt] *= sc;
                #pragma unroll
                for (int dt = 0; dt < 4; dt++)
                    #pragma unroll
                    for (int r = 0; r < 4; r++) acc[qt][dt][r] *= sc;
            }
            const float mref = mrow[qt];
            float p[8]; float ps = 0.f;
            #pragma unroll
            for (int r = 0; r < 4; r++) { p[r] = __expf(S[0][qt][r] - mref); ps += p[r]; }
            #pragma unroll
            for (int r = 0; r < 4; r++) { p[4 + r] = __expf(S[1][qt][r] - mref); ps += p[4 + r]; }
            ps += __shfl_xor(ps, 16);
            ps += __shfl_xor(ps, 32);
            lrow[qt] += ps;
            // S C-frag already matches PV B-frag (i<4 from t=0, i>=4 t=1)
            #pragma unroll
            for (int i = 0; i < 8; i++) pB[qt][i] = (_Float16)p[i];
        }
        #pragma unroll
        for (int dt = 0; dt < 4; dt++) {
            acc[0][dt] = MFMA16(vA[dt], pB[0], acc[0][dt]);
            acc[1][dt] = MFMA16(vA[dt], pB[1], acc[1][dt]);
        }
    }

    // ---------------- epilogue: out = (agg/l) @ Wv^T + bv ----------------
    #pragma unroll
    for (int qt = 0; qt < 2; qt++) {
        const float rl = 1.f / lrow[qt];
        #pragma unroll
        for (int dt = 0; dt < 4; dt++)
            #pragma unroll
            for (int r = 0; r < 4; r++) acc[qt][dt][r] *= rl;
    }
    half8 wf[4][2];
    #pragma unroll
    for (int mt = 0; mt < 4; mt++)
        #pragma unroll
        for (int ks = 0; ks < 2; ks++) {
            const float* wp = Wv + (size_t)(mt * 16 + c) * 64 + ks * 32 + Q * 8;
            #pragma unroll
            for (int i = 0; i < 8; i++) wf[mt][ks][i] = (_Float16)wp[i];
        }
    const int srcA = 32 * (Q & 1) + c;
    const int srcB = srcA + 16;
    const bool hi = (Q >> 1) & 1;
    f32x4 o[2][4];
    #pragma unroll
    for (int qt = 0; qt < 2; qt++) {
        half8 pe[2];
        #pragma unroll
        for (int ks = 0; ks < 2; ks++) {
            #pragma unroll
            for (int r = 0; r < 4; r++) {
                float a0 = __shfl(acc[qt][2 * ks + 0][r], srcA);
                float a1 = __shfl(acc[qt][2 * ks + 1][r], srcA);
                float b0 = __shfl(acc[qt][2 * ks + 0][r], srcB);
                float b1 = __shfl(acc[qt][2 * ks + 1][r], srcB);
                pe[ks][r]     = (_Float16)(hi ? a1 : a0);
                pe[ks][4 + r] = (_Float16)(hi ? b1 : b0);
            }
        }
        #pragma unroll
        for (int mt = 0; mt < 4; mt++) {
            f32x4 t = MFMA16(wf[mt][0], pe[0], zero4());
            o[qt][mt] = MFMA16(wf[mt][1], pe[1], t);
        }
    }
    float4 bf[4];
    #pragma unroll
    for (int mt = 0; mt < 4; mt++) bf[mt] = *(const float4*)(bv + mt * 16 + 4 * Q);
    #pragma unroll
    for (int qt = 0; qt < 2; qt++) {
        const int row = rbase + qt * 16 + c;
        if (row < N_ROWS) {
            #pragma unroll
            for (int mt = 0; mt < 4; mt++) {
                float4 vv = make_float4(o[qt][mt][0] + bf[mt].x, o[qt][mt][1] + bf[mt].y,
                                        o[qt][mt][2] + bf[mt].z, o[qt][mt][3] + bf[mt].w);
                *(float4*)(out + (size_t)row * 64 + mt * 16 + 4 * Q) = vv;
            }
        }
    }
}

extern "C" void kernel_launch(void* const* d_in, const int* in_sizes, int n_in,
                              void* d_out, int out_size, void* d_ws, size_t ws_size,
                              hipStream_t stream)
{
    const float* x  = (const float*)d_in[0];
    const float* nb = (const float*)d_in[1];
    const float* Wq = (const float*)d_in[2];
    const float* bq = (const float*)d_in[3];
    const float* Wk = (const float*)d_in[4];
    // d_in[5] = bk: provably cancels in softmax -> unused
    const float* Wv = (const float*)d_in[6];
    const float* bv = (const float*)d_in[7];
    float* out = (float*)d_out;

    char* ws = (char*)d_ws;                                  // needs ~300KB
    unsigned short* Gh  = (unsigned short*)(ws);             // 9216 B
    unsigned short* Gl  = (unsigned short*)(ws + 9216);      // 9216 B
    float*          uW  = (float*)(ws + 18432);              // 256 B
    unsigned short* Kp  = (unsigned short*)(ws + 18688);     // 147456 B
    unsigned short* VTp = (unsigned short*)(ws + 166144);    // 133120 B (end 299264)

    prep_kernel<<<17, 256, 0, stream>>>(nb, Wq, bq, Wk, Gh, Gl, uW, Kp, VTp);
    const int grid = (N_ROWS + 127) / 128;   // 782 blocks x 256 threads
    attn_kernel<<<grid, 256, 0, stream>>>(x, Gh, Gl, uW, Kp, VTp, Wv, bv, out);
}

// Round 2
// 161.680 us; speedup vs baseline: 1.2307x; 1.0351x over previous
//
#include <hip/hip_runtime.h>

// RelationGAT fused flash-attention, MFMA fp16 (gfx950) -- R9 "1-wave blocks + shuffle-free softmax".
// out = softmax((x@Wq^T+bq) @ (nb@Wk^T+bk)^T) @ nb @ Wv^T + bv
// bk cancels in softmax. Q~ = x@G + u, G = Wq^T Wk, u = bq^T Wk; K=V=raw nb.
//
// R9 theory: R8 (96us) was still stall-bound: occupancy 20% (782 4-wave blocks =
// 3.05/CU, coarse quantum + tail) and 8 DS shuffles/iter on the softmax critical
// path (~500cyc/iter un-hideable at 1.6 waves/SIMD).
// Fixes: (a) 1-wave blocks, 32 rows each -> grid 3125 = 100000/32 exactly,
// 12.2 blocks/CU, fine scheduling, zero row padding; (b) shuffle-FREE fast path:
// __any(local max > mrow+8) gate (VOPC, no DS) + per-lane lrow partials reduced
// once in epilogue; slow path (2 shfl + rescale) is rare; (c) double-buffered
// K-fragment prefetch so L2 latency hides under softmax/PV.
//
// Workspace layout (needs ~300KB):
//   [0,9216)        Gh   fp16 [64][72]   G^T hi
//   [9216,18432)    Gl   fp16 [64][72]   G^T lo
//   [18432,18688)   uW   f32  [64]
//   [18688,166144)  Kp   fp16 [1024][72] rows permuted within 32-groups
//   [166144,299264) VTp  fp16 [64][1040] d-major transpose of nb

#define N_ROWS 100000
#define VT_STRIDE 1040

typedef __attribute__((ext_vector_type(8))) _Float16 half8;
typedef __attribute__((ext_vector_type(4))) float    f32x4;

#define MFMA16(a,b,c) __builtin_amdgcn_mfma_f32_16x16x32_f16((a),(b),(c),0,0,0)

static __device__ __forceinline__ f32x4 zero4() {
    f32x4 v = {0.f, 0.f, 0.f, 0.f};
    return v;
}

// ---------------- prep: G^T hi/lo + u (block 0), nb -> Kp/VTp fp16 (blocks 1..16) ----------------
__global__ __launch_bounds__(256)
void prep_kernel(const float* __restrict__ nb, const float* __restrict__ Wq,
                 const float* __restrict__ bq, const float* __restrict__ Wk,
                 unsigned short* __restrict__ Gh, unsigned short* __restrict__ Gl,
                 float* __restrict__ uW, unsigned short* __restrict__ Kp,
                 unsigned short* __restrict__ VTp)
{
    __shared__ __align__(16) float sm[8192];   // 32KB: blk0 Wk|Wq, blks>0 transpose tile
    const int tid = threadIdx.x;
    if (blockIdx.x == 0) {
        const float4* wk4 = (const float4*)Wk;
        const float4* wq4 = (const float4*)Wq;
        float4* dk = (float4*)sm;
        float4* dq = (float4*)(sm + 4096);
        #pragma unroll
        for (int u = 0; u < 4; u++) {
            dk[u * 256 + tid] = wk4[u * 256 + tid];
            dq[u * 256 + tid] = wq4[u * 256 + tid];
        }
        __syncthreads();
        const int e2 = tid & 63, e1g = (tid >> 6) * 16;
        float g[16];
        #pragma unroll
        for (int q = 0; q < 16; q++) g[q] = 0.f;
        for (int w = 0; w < 64; w++) {
            float kv = sm[w * 64 + e2];
            const float* wqp = sm + 4096 + w * 64 + e1g;
            #pragma unroll
            for (int q = 0; q < 16; q++) g[q] = fmaf(wqp[q], kv, g[q]);
        }
        union { half8 h; uint4 u; } ph0, pl0, ph1, pl1;
        #pragma unroll
        for (int i = 0; i < 8; i++) {
            _Float16 h0 = (_Float16)g[i];
            ph0.h[i] = h0; pl0.h[i] = (_Float16)(g[i] - (float)h0);
            _Float16 h1 = (_Float16)g[8 + i];
            ph1.h[i] = h1; pl1.h[i] = (_Float16)(g[8 + i] - (float)h1);
        }
        *(uint4*)(Gh + e2 * 72 + e1g)     = ph0.u;
        *(uint4*)(Gh + e2 * 72 + e1g + 8) = ph1.u;
        *(uint4*)(Gl + e2 * 72 + e1g)     = pl0.u;
        *(uint4*)(Gl + e2 * 72 + e1g + 8) = pl1.u;
        if (tid < 64) {
            float uu = 0.f;
            for (int w = 0; w < 64; w++) uu = fmaf(bq[w], sm[w * 64 + tid], uu);
            uW[tid] = uu;
        }
    } else {
        const int j0 = (blockIdx.x - 1) * 64;    // this block's 64 keys
        const int jr = tid >> 2;                 // 0..63 local key row
        const int c0 = (tid & 3) * 16;           // 16-elem d chunk
        const float* np = nb + (size_t)(j0 + jr) * 64 + c0;
        float a[16];
        #pragma unroll
        for (int u = 0; u < 4; u++) *(float4*)(a + 4 * u) = *(const float4*)(np + 4 * u);
        // Kp: physical row permutation within 32-group: j=[Q1 Q0 t r1 r0] -> p=[t Q1 Q0 r1 r0]
        const int pr = (jr & ~31) | (((jr >> 2) & 1) << 4) | (((jr >> 3) & 3) << 2) | (jr & 3);
        union { half8 h; uint4 u; } pk0, pk1;
        #pragma unroll
        for (int i = 0; i < 8; i++) { pk0.h[i] = (_Float16)a[i]; pk1.h[i] = (_Float16)a[8 + i]; }
        *(uint4*)(Kp + (size_t)(j0 + pr) * 72 + c0)     = pk0.u;
        *(uint4*)(Kp + (size_t)(j0 + pr) * 72 + c0 + 8) = pk1.u;
        // VTp: transpose via LDS [64][65] f32 (65: conflict-free column reads)
        #pragma unroll
        for (int i = 0; i < 16; i++) sm[jr * 65 + c0 + i] = a[i];
        __syncthreads();
        const int d   = tid >> 2;
        const int jc0 = (tid & 3) * 16;
        union { half8 h; uint4 u; } pv0, pv1;
        #pragma unroll
        for (int i = 0; i < 8; i++) {
            pv0.h[i] = (_Float16)sm[(jc0 + i) * 65 + d];
            pv1.h[i] = (_Float16)sm[(jc0 + 8 + i) * 65 + d];
        }
        *(uint4*)(VTp + (size_t)d * VT_STRIDE + j0 + jc0)     = pv0.u;
        *(uint4*)(VTp + (size_t)d * VT_STRIDE + j0 + jc0 + 8) = pv1.u;
    }
}

// One 32-key flash step: issue V[jb] + prefetch K[jn] into (nk0,nk1), compute with (ck0,ck1).
static __device__ __forceinline__ void flash_step(
    int jb, int jn, int c, int Q,
    const unsigned short* __restrict__ Kp, const unsigned short* __restrict__ VTp,
    const half8 (&ck0)[2], const half8 (&ck1)[2],
    half8 (&nk0)[2], half8 (&nk1)[2],
    const half8 (&qh)[2][2], const half8 (&ql)[2][2],
    f32x4 (&acc)[2][4], float (&mrow)[2], float (&lrow)[2])
{
    // V frags for THIS tile -- consumed ~300cyc later at PV, L2 latency hidden
    half8 vA[4];
    #pragma unroll
    for (int dt = 0; dt < 4; dt++)
        vA[dt] = *(const half8*)(VTp + (size_t)(dt * 16 + c) * VT_STRIDE + jb + Q * 8);
    // K frags for NEXT tile
    #pragma unroll
    for (int t = 0; t < 2; t++) {
        const unsigned short* kp = Kp + (size_t)(jn + 16 * t + c) * 72;
        nk0[t] = *(const half8*)(kp + Q * 8);
        nk1[t] = *(const half8*)(kp + 32 + Q * 8);
    }
    // S tiles; logical j of S-frag lane(Q,c) reg r = jb + 8Q + 4t + r
    f32x4 S[2][2];   // [t][qt]
    #pragma unroll
    for (int t = 0; t < 2; t++)
        #pragma unroll
        for (int qt = 0; qt < 2; qt++) {
            f32x4 s = MFMA16(ck0[t], qh[qt][0], zero4());
            s = MFMA16(ck1[t], qh[qt][1], s);
            s = MFMA16(ck0[t], ql[qt][0], s);
            s = MFMA16(ck1[t], ql[qt][1], s);
            S[t][qt] = s;
        }
    half8 pB[2];
    #pragma unroll
    for (int qt = 0; qt < 2; qt++) {
        // local (per-lane) tile max only -- NO cross-lane reduce in fast path
        float pmax = fmaxf(fmaxf(fmaxf(S[0][qt][0], S[0][qt][1]),
                                 fmaxf(S[0][qt][2], S[0][qt][3])),
                           fmaxf(fmaxf(S[1][qt][0], S[1][qt][1]),
                                 fmaxf(S[1][qt][2], S[1][qt][3])));
        // defer-max (T13): wave-uniform gate via __any (VOPC+exec, zero DS ops).
        // Math exact: p bounded by e^8 ~ 2981, fine in fp16/f32 accum.
        if (__any(pmax > mrow[qt] + 8.f)) {
            float cm = pmax;
            cm = fmaxf(cm, __shfl_xor(cm, 16));
            cm = fmaxf(cm, __shfl_xor(cm, 32));   // uniform per q-row c across quads
            const float mn = fmaxf(mrow[qt], cm);
            const float sc = __expf(mrow[qt] - mn);
            mrow[qt] = mn;
            lrow[qt] *= sc;
            #pragma unroll
            for (int dt = 0; dt < 4; dt++)
                #pragma unroll
                for (int r = 0; r < 4; r++) acc[qt][dt][r] *= sc;
        }
        const float mref = mrow[qt];
        float p[8]; float ps = 0.f;
        #pragma unroll
        for (int r = 0; r < 4; r++) { p[r] = __expf(S[0][qt][r] - mref); ps += p[r]; }
        #pragma unroll
        for (int r = 0; r < 4; r++) { p[4 + r] = __expf(S[1][qt][r] - mref); ps += p[4 + r]; }
        lrow[qt] += ps;   // per-lane PARTIAL (this lane's 8 keys); reduced once in epilogue
        // S C-frag already matches PV B-frag (i<4 from t=0, i>=4 t=1)
        #pragma unroll
        for (int i = 0; i < 8; i++) pB[qt][i] = (_Float16)p[i];
    }
    #pragma unroll
    for (int dt = 0; dt < 4; dt++) {
        acc[0][dt] = MFMA16(vA[dt], pB[0], acc[0][dt]);
        acc[1][dt] = MFMA16(vA[dt], pB[1], acc[1][dt]);
    }
}

// ---------------- main: 1-wave blocks, barrier-free, K/V frags straight from L2 ----------------
__global__ __launch_bounds__(64, 3)
void attn_kernel(const float* __restrict__ x,
                 const unsigned short* __restrict__ Gh,
                 const unsigned short* __restrict__ Gl,
                 const float* __restrict__ uW,
                 const unsigned short* __restrict__ Kp,
                 const unsigned short* __restrict__ VTp,
                 const float* __restrict__ Wv,
                 const float* __restrict__ bv,
                 float* __restrict__ out)
{
    __shared__ __align__(16) float slice[1088];   // [16][68] f32 Q-transpose slice (wave-private)
    const int lane = threadIdx.x & 63;
    const int Q    = lane >> 4;    // quad 0..3
    const int c    = lane & 15;    // col 0..15
    const int rbase = blockIdx.x * 32;   // this wave's 32 q-rows (3125*32 = 100000 exactly)

    // ------- setup: Q~^T = G^T x^T via MFMA (G from L2) -> q-frags hi/lo -------
    half8 qh[2][2], ql[2][2];   // [rt][ks] -- static indices ONLY
    #pragma unroll
    for (int rt = 0; rt < 2; rt++) {
        int row = rbase + rt * 16 + c;
        if (row > N_ROWS - 1) row = N_ROWS - 1;
        half8 xh[2], xl[2];
        #pragma unroll
        for (int ks = 0; ks < 2; ks++) {
            const float* xp = x + (size_t)row * 64 + ks * 32 + Q * 8;
            float a[8];
            *(float4*)a       = *(const float4*)xp;
            *(float4*)(a + 4) = *(const float4*)(xp + 4);
            #pragma unroll
            for (int i = 0; i < 8; i++) {
                _Float16 h = (_Float16)a[i];
                xh[ks][i] = h;
                xl[ks][i] = (_Float16)(a[i] - (float)h);
            }
        }
        #pragma unroll
        for (int mt = 0; mt < 4; mt++) {
            f32x4 Cm = zero4();
            #pragma unroll
            for (int ks = 0; ks < 2; ks++) {
                half8 gh = *(const half8*)(Gh + (mt * 16 + c) * 72 + ks * 32 + Q * 8);
                half8 gl = *(const half8*)(Gl + (mt * 16 + c) * 72 + ks * 32 + Q * 8);
                Cm = MFMA16(gh, xh[ks], Cm);   // D[dout][x-row]
                Cm = MFMA16(gh, xl[ks], Cm);
                Cm = MFMA16(gl, xh[ks], Cm);
            }
            // C row = dout mt*16+4Q+r, col = x-row c -> slice[x-row][dout]
            *(f32x4*)(slice + c * 68 + mt * 16 + 4 * Q) = Cm;
        }
        __builtin_amdgcn_s_waitcnt(0);   // wave-local LDS RAW
        #pragma unroll
        for (int ks = 0; ks < 2; ks++) {
            const float* qp = slice + c * 68 + ks * 32 + Q * 8;
            const float* up = uW + ks * 32 + Q * 8;
            #pragma unroll
            for (int i = 0; i < 8; i++) {
                float val = qp[i] + up[i];
                _Float16 h = (_Float16)val;
                qh[rt][ks][i] = h;
                ql[rt][ks][i] = (_Float16)(val - (float)h);
            }
        }
        __builtin_amdgcn_s_waitcnt(0);   // reads done before rt=1 overwrites slice
    }

    // ---------------- flash loop: 1024 keys, 32/step, K double-buffer prefetch ----------------
    f32x4 acc[2][4];   // [qt][dt] agg^T C-frags (static idx only)
    #pragma unroll
    for (int qt = 0; qt < 2; qt++)
        #pragma unroll
        for (int dt = 0; dt < 4; dt++) acc[qt][dt] = zero4();
    float mrow[2] = { -3.0e38f, -3.0e38f };
    float lrow[2] = { 0.f, 0.f };

    half8 ka0[2], ka1[2], kb0[2], kb1[2];
    #pragma unroll
    for (int t = 0; t < 2; t++) {                 // preload tile 0 into A-buffer
        const unsigned short* kp = Kp + (size_t)(16 * t + c) * 72;
        ka0[t] = *(const half8*)(kp + Q * 8);
        ka1[t] = *(const half8*)(kp + 32 + Q * 8);
    }
    #pragma unroll 1
    for (int jj = 0; jj < 16; jj++) {
        const int jb = jj * 64;
        flash_step(jb,      jb + 32, c, Q, Kp, VTp, ka0, ka1, kb0, kb1, qh, ql, acc, mrow, lrow);
        const int jn2 = (jb + 64 < 1024) ? jb + 64 : jb + 32;   // clamp last prefetch
        flash_step(jb + 32, jn2,     c, Q, Kp, VTp, kb0, kb1, ka0, ka1, qh, ql, acc, mrow, lrow);
    }

    // ---------------- epilogue: reduce lrow partials, out = (agg/l) @ Wv^T + bv ----------------
    #pragma unroll
    for (int qt = 0; qt < 2; qt++) {
        float l = lrow[qt];
        l += __shfl_xor(l, 16);
        l += __shfl_xor(l, 32);     // once per kernel, not per iter
        const float rl = 1.f / l;
        #pragma unroll
        for (int dt = 0; dt < 4; dt++)
            #pragma unroll
            for (int r = 0; r < 4; r++) acc[qt][dt][r] *= rl;
    }
    half8 wf[4][2];
    #pragma unroll
    for (int mt = 0; mt < 4; mt++)
        #pragma unroll
        for (int ks = 0; ks < 2; ks++) {
            const float* wp = Wv + (size_t)(mt * 16 + c) * 64 + ks * 32 + Q * 8;
            #pragma unroll
            for (int i = 0; i < 8; i++) wf[mt][ks][i] = (_Float16)wp[i];
        }
    const int srcA = 32 * (Q & 1) + c;
    const int srcB = srcA + 16;
    const bool hi = (Q >> 1) & 1;
    f32x4 o[2][4];
    #pragma unroll
    for (int qt = 0; qt < 2; qt++) {
        half8 pe[2];
        #pragma unroll
        for (int ks = 0; ks < 2; ks++) {
            #pragma unroll
            for (int r = 0; r < 4; r++) {
                float a0 = __shfl(acc[qt][2 * ks + 0][r], srcA);
                float a1 = __shfl(acc[qt][2 * ks + 1][r], srcA);
                float b0 = __shfl(acc[qt][2 * ks + 0][r], srcB);
                float b1 = __shfl(acc[qt][2 * ks + 1][r], srcB);
                pe[ks][r]     = (_Float16)(hi ? a1 : a0);
                pe[ks][4 + r] = (_Float16)(hi ? b1 : b0);
            }
        }
        #pragma unroll
        for (int mt = 0; mt < 4; mt++) {
            f32x4 t = MFMA16(wf[mt][0], pe[0], zero4());
            o[qt][mt] = MFMA16(wf[mt][1], pe[1], t);
        }
    }
    float4 bf[4];
    #pragma unroll
    for (int mt = 0; mt < 4; mt++) bf[mt] = *(const float4*)(bv + mt * 16 + 4 * Q);
    #pragma unroll
    for (int qt = 0; qt < 2; qt++) {
        const int row = rbase + qt * 16 + c;
        if (row < N_ROWS) {
            #pragma unroll
            for (int mt = 0; mt < 4; mt++) {
                float4 vv = make_float4(o[qt][mt][0] + bf[mt].x, o[qt][mt][1] + bf[mt].y,
                                        o[qt][mt][2] + bf[mt].z, o[qt][mt][3] + bf[mt].w);
                *(float4*)(out + (size_t)row * 64 + mt * 16 + 4 * Q) = vv;
            }
        }
    }
}

extern "C" void kernel_launch(void* const* d_in, const int* in_sizes, int n_in,
                              void* d_out, int out_size, void* d_ws, size_t ws_size,
                              hipStream_t stream)
{
    const float* x  = (const float*)d_in[0];
    const float* nb = (const float*)d_in[1];
    const float* Wq = (const float*)d_in[2];
    const float* bq = (const float*)d_in[3];
    const float* Wk = (const float*)d_in[4];
    // d_in[5] = bk: provably cancels in softmax -> unused
    const float* Wv = (const float*)d_in[6];
    const float* bv = (const float*)d_in[7];
    float* out = (float*)d_out;

    char* ws = (char*)d_ws;                                  // needs ~300KB
    unsigned short* Gh  = (unsigned short*)(ws);             // 9216 B
    unsigned short* Gl  = (unsigned short*)(ws + 9216);      // 9216 B
    float*          uW  = (float*)(ws + 18432);              // 256 B
    unsigned short* Kp  = (unsigned short*)(ws + 18688);     // 147456 B
    unsigned short* VTp = (unsigned short*)(ws + 166144);    // 133120 B (end 299264)

    prep_kernel<<<17, 256, 0, stream>>>(nb, Wq, bq, Wk, Gh, Gl, uW, Kp, VTp);
    const int grid = N_ROWS / 32;   // 3125 1-wave blocks, 32 rows each, zero padding
    attn_kernel<<<grid, 64, 0, stream>>>(x, Gh, Gl, uW, Kp, VTp, Wv, bv, out);
}

// Round 3
// 149.164 us; speedup vs baseline: 1.3339x; 1.0839x over previous
//
#include <hip/hip_runtime.h>

// RelationGAT fused flash-attention, MFMA fp16 (gfx950) -- R10 "fragment-major K/V".
// out = softmax((x@Wq^T+bq) @ (nb@Wk^T+bk)^T) @ nb @ Wv^T + bv
// bk cancels in softmax. Q~ = x@G + u, G = Wq^T Wk, u = bq^T Wk; K=V=raw nb.
//
// R10 theory: R9 (86us) still latency-stalled (~2100cyc/step vs ~300cyc issue
// content; MfmaUtil 20% == 16.4us MFMA floor / 86us). Root cause: every K/V load
// gathered 16B x 64 lanes from 16 NON-CONTIGUOUS cache lines (Kp stride 144B,
// VTp stride 2080B) -> 128 scattered line transactions/step through L1; V loaded
// ~250cyc before use (under L2 latency budget). Fixes:
//  (a) fragment-major layouts KF/VF/GF: prep emits exactly the bytes each lane's
//      MFMA fragment needs -> every loop load is ONE contiguous 1KB wave-block
//      (SGPR base + const voffset + imm offset), key-permutation baked in so the
//      S-frag <-> PV B-frag pairing is unchanged;
//  (b) V next-tile reload in-place after PV (zero extra VGPRs) -> full-step
//      latency budget for V, matching K's double buffer.
// exp2-domain rejected: ~1.5% VALU for a numerics risk vs unknown absmax bound.
//
// Workspace layout (278784 B):
//   [0,8192)         GFh  fp16 frag-major G^T hi: [f=mt*2+ks][lane][8]
//   [8192,16384)     GFl  fp16 frag-major G^T lo
//   [16384,16640)    uW   f32 [64]
//   [16640,147712)   KF   fp16 [tile][f=t*2+h][lane][8], key-permuted
//   [147712,278784)  VF   fp16 [tile][dt][lane][8], natural key order

#define N_ROWS 100000

typedef __attribute__((ext_vector_type(8))) _Float16 half8;
typedef __attribute__((ext_vector_type(4))) float    f32x4;

#define MFMA16(a,b,c) __builtin_amdgcn_mfma_f32_16x16x32_f16((a),(b),(c),0,0,0)

static __device__ __forceinline__ f32x4 zero4() {
    f32x4 v = {0.f, 0.f, 0.f, 0.f};
    return v;
}

// ---------------- prep: GF hi/lo + u (block 0), nb -> KF/VF fp16 (blocks 1..16) ----------------
__global__ __launch_bounds__(256)
void prep_kernel(const float* __restrict__ nb, const float* __restrict__ Wq,
                 const float* __restrict__ bq, const float* __restrict__ Wk,
                 unsigned short* __restrict__ GFh, unsigned short* __restrict__ GFl,
                 float* __restrict__ uW, unsigned short* __restrict__ KF,
                 unsigned short* __restrict__ VF)
{
    __shared__ __align__(16) float sm[8192];   // 32KB: blk0 Wk|Wq, blks>0 transpose tile
    const int tid = threadIdx.x;
    if (blockIdx.x == 0) {
        const float4* wk4 = (const float4*)Wk;
        const float4* wq4 = (const float4*)Wq;
        float4* dk = (float4*)sm;
        float4* dq = (float4*)(sm + 4096);
        #pragma unroll
        for (int u = 0; u < 4; u++) {
            dk[u * 256 + tid] = wk4[u * 256 + tid];
            dq[u * 256 + tid] = wq4[u * 256 + tid];
        }
        __syncthreads();
        const int e2 = tid & 63, e1g = (tid >> 6) * 16;
        float g[16];
        #pragma unroll
        for (int q = 0; q < 16; q++) g[q] = 0.f;
        for (int w = 0; w < 64; w++) {
            float kv = sm[w * 64 + e2];
            const float* wqp = sm + 4096 + w * 64 + e1g;
            #pragma unroll
            for (int q = 0; q < 16; q++) g[q] = fmaf(wqp[q], kv, g[q]);
        }
        union { half8 h; uint4 u; } ph0, pl0, ph1, pl1;
        #pragma unroll
        for (int i = 0; i < 8; i++) {
            _Float16 h0 = (_Float16)g[i];
            ph0.h[i] = h0; pl0.h[i] = (_Float16)(g[i] - (float)h0);
            _Float16 h1 = (_Float16)g[8 + i];
            ph1.h[i] = h1; pl1.h[i] = (_Float16)(g[8 + i] - (float)h1);
        }
        // frag-major: f = mt*2+ks, lane = Q*16+c ; this thread owns row e2 ->
        // (mt = e2>>4, c = e2&15), cols e1g..e1g+15 -> ks = tid>>7, Q0 = 2*((tid>>6)&1)
        const int mt = e2 >> 4, cc = e2 & 15;
        const int ks = tid >> 7, Q0 = 2 * ((tid >> 6) & 1);
        const int f  = mt * 2 + ks;
        *(uint4*)(GFh + (f * 64 + Q0 * 16 + cc) * 8)       = ph0.u;
        *(uint4*)(GFh + (f * 64 + (Q0 + 1) * 16 + cc) * 8) = ph1.u;
        *(uint4*)(GFl + (f * 64 + Q0 * 16 + cc) * 8)       = pl0.u;
        *(uint4*)(GFl + (f * 64 + (Q0 + 1) * 16 + cc) * 8) = pl1.u;
        if (tid < 64) {
            float uu = 0.f;
            for (int w = 0; w < 64; w++) uu = fmaf(bq[w], sm[w * 64 + tid], uu);
            uW[tid] = uu;
        }
    } else {
        const int j0 = (blockIdx.x - 1) * 64;    // this block's 64 keys (2 tiles)
        const int T0 = (blockIdx.x - 1) * 2;
        // stage 64x64 f32 tile to LDS [64][65] for the VF transpose
        {
            const int jr = tid >> 2, c0 = (tid & 3) * 16;
            const float* np = nb + (size_t)(j0 + jr) * 64 + c0;
            #pragma unroll
            for (int u = 0; u < 4; u++) {
                float4 v = *(const float4*)(np + 4 * u);
                sm[jr * 65 + c0 + 4 * u]     = v.x;
                sm[jr * 65 + c0 + 4 * u + 1] = v.y;
                sm[jr * 65 + c0 + 4 * u + 2] = v.z;
                sm[jr * 65 + c0 + 4 * u + 3] = v.w;
            }
        }
        // KF direct from global: slot -> (tt, f=(t,h), lane=(Q,c)); stored key row is the
        // PERMUTED key keyof(t,c) so that S-frag reg r at lane(Q,c) = key 8Q+4t+r (as R9).
        #pragma unroll
        for (int s = 0; s < 2; s++) {
            const int slot = tid + 256 * s;
            const int tt = (slot >> 8) & 1, f = (slot >> 6) & 3, ln = slot & 63;
            const int t = f >> 1, h = f & 1, Qw = ln >> 4, cw = ln & 15;
            const int key = ((cw >> 3) & 1) * 16 + ((cw >> 2) & 1) * 8 + 4 * t + (cw & 3);
            const float* kp = nb + (size_t)((T0 + tt) * 32 + key) * 64 + h * 32 + Qw * 8;
            float b[8];
            *(float4*)b       = *(const float4*)kp;
            *(float4*)(b + 4) = *(const float4*)(kp + 4);
            union { half8 hh; uint4 u; } pk;
            #pragma unroll
            for (int i = 0; i < 8; i++) pk.hh[i] = (_Float16)b[i];
            *(uint4*)(KF + (size_t)(T0 + tt) * 2048 + f * 512 + ln * 8) = pk.u;
        }
        __syncthreads();
        // VF from LDS transpose: vA[dt][i] = V^T[dt*16+c][T*32 + Q*8 + i] (natural order)
        #pragma unroll
        for (int s = 0; s < 2; s++) {
            const int slot = tid + 256 * s;
            const int tt = (slot >> 8) & 1, dt = (slot >> 6) & 3, ln = slot & 63;
            const int Qw = ln >> 4, cw = ln & 15;
            union { half8 hh; uint4 u; } pv;
            #pragma unroll
            for (int i = 0; i < 8; i++)
                pv.hh[i] = (_Float16)sm[(tt * 32 + Qw * 8 + i) * 65 + dt * 16 + cw];
            *(uint4*)(VF + (size_t)(T0 + tt) * 2048 + dt * 512 + ln * 8) = pv.u;
        }
    }
}

// One 32-key flash step: compute with ck/vA, prefetch K[Tn] into nk, reload vA <- V[Tn].
static __device__ __forceinline__ void flash_step(
    const unsigned short* __restrict__ kfl, const unsigned short* __restrict__ vfl,
    int Tn,
    const half8 (&ck)[4], half8 (&nk)[4], half8 (&vA)[4],
    const half8 (&qh)[2][2], const half8 (&ql)[2][2],
    f32x4 (&acc)[2][4], float (&mrow)[2], float (&lrow)[2])
{
    // prefetch next tile's K frags -- contiguous 1KB per instr, imm offsets
    const unsigned short* kn = kfl + Tn * 2048;
    #pragma unroll
    for (int f = 0; f < 4; f++) nk[f] = *(const half8*)(kn + f * 512);

    // S tiles; logical key of S-frag lane(Q,c) reg r = T*32 + 8Q + 4t + r
    f32x4 S[2][2];   // [t][qt]
    #pragma unroll
    for (int t = 0; t < 2; t++)
        #pragma unroll
        for (int qt = 0; qt < 2; qt++) {
            f32x4 s = MFMA16(ck[2 * t],     qh[qt][0], zero4());
            s = MFMA16(ck[2 * t + 1], qh[qt][1], s);
            s = MFMA16(ck[2 * t],     ql[qt][0], s);
            s = MFMA16(ck[2 * t + 1], ql[qt][1], s);
            S[t][qt] = s;
        }
    half8 pB[2];
    #pragma unroll
    for (int qt = 0; qt < 2; qt++) {
        // local (per-lane) tile max only -- NO cross-lane reduce in fast path
        float pmax = fmaxf(fmaxf(fmaxf(S[0][qt][0], S[0][qt][1]),
                                 fmaxf(S[0][qt][2], S[0][qt][3])),
                           fmaxf(fmaxf(S[1][qt][0], S[1][qt][1]),
                                 fmaxf(S[1][qt][2], S[1][qt][3])));
        // defer-max (T13): wave-uniform gate via __any (VOPC+exec, zero DS ops).
        // Math exact: p bounded by e^8 ~ 2981, fine in fp16/f32 accum.
        if (__any(pmax > mrow[qt] + 8.f)) {
            float cm = pmax;
            cm = fmaxf(cm, __shfl_xor(cm, 16));
            cm = fmaxf(cm, __shfl_xor(cm, 32));   // uniform per q-row c across quads
            const float mn = fmaxf(mrow[qt], cm);
            const float sc = __expf(mrow[qt] - mn);
            mrow[qt] = mn;
            lrow[qt] *= sc;
            #pragma unroll
            for (int dt = 0; dt < 4; dt++)
                #pragma unroll
                for (int r = 0; r < 4; r++) acc[qt][dt][r] *= sc;
        }
        const float mref = mrow[qt];
        float p[8]; float ps = 0.f;
        #pragma unroll
        for (int r = 0; r < 4; r++) { p[r] = __expf(S[0][qt][r] - mref); ps += p[r]; }
        #pragma unroll
        for (int r = 0; r < 4; r++) { p[4 + r] = __expf(S[1][qt][r] - mref); ps += p[4 + r]; }
        lrow[qt] += ps;   // per-lane PARTIAL (this lane's 8 keys); reduced once in epilogue
        // S C-frag matches PV B-frag (i<4 from t=0, i>=4 t=1) via the KF key permutation
        #pragma unroll
        for (int i = 0; i < 8; i++) pB[qt][i] = (_Float16)p[i];
    }
    #pragma unroll
    for (int dt = 0; dt < 4; dt++) {
        acc[0][dt] = MFMA16(vA[dt], pB[0], acc[0][dt]);
        acc[1][dt] = MFMA16(vA[dt], pB[1], acc[1][dt]);
    }
    // reload vA in-place from next tile (WAR after PV issue; full-step latency budget)
    const unsigned short* vn = vfl + Tn * 2048;
    #pragma unroll
    for (int d = 0; d < 4; d++) vA[d] = *(const half8*)(vn + d * 512);
}

// ---------------- main: 1-wave blocks, barrier-free, frag-major K/V from L2 ----------------
__global__ __launch_bounds__(64, 3)
void attn_kernel(const float* __restrict__ x,
                 const unsigned short* __restrict__ GFh,
                 const unsigned short* __restrict__ GFl,
                 const float* __restrict__ uW,
                 const unsigned short* __restrict__ KF,
                 const unsigned short* __restrict__ VF,
                 const float* __restrict__ Wv,
                 const float* __restrict__ bv,
                 float* __restrict__ out)
{
    __shared__ __align__(16) float slice[1088];   // [16][68] f32 Q-transpose slice (wave-private)
    const int lane = threadIdx.x & 63;
    const int Q    = lane >> 4;    // quad 0..3
    const int c    = lane & 15;    // col 0..15
    const int rbase = blockIdx.x * 32;   // this wave's 32 q-rows (3125*32 = 100000 exactly)

    // ------- setup: Q~^T = G^T x^T via MFMA (frag-major G from L2) -> q-frags hi/lo -------
    half8 qh[2][2], ql[2][2];   // [rt][ks] -- static indices ONLY
    #pragma unroll
    for (int rt = 0; rt < 2; rt++) {
        int row = rbase + rt * 16 + c;
        if (row > N_ROWS - 1) row = N_ROWS - 1;
        half8 xh[2], xl[2];
        #pragma unroll
        for (int ks = 0; ks < 2; ks++) {
            const float* xp = x + (size_t)row * 64 + ks * 32 + Q * 8;
            float a[8];
            *(float4*)a       = *(const float4*)xp;
            *(float4*)(a + 4) = *(const float4*)(xp + 4);
            #pragma unroll
            for (int i = 0; i < 8; i++) {
                _Float16 h = (_Float16)a[i];
                xh[ks][i] = h;
                xl[ks][i] = (_Float16)(a[i] - (float)h);
            }
        }
        #pragma unroll
        for (int mt = 0; mt < 4; mt++) {
            f32x4 Cm = zero4();
            #pragma unroll
            for (int ks = 0; ks < 2; ks++) {
                half8 gh = *(const half8*)(GFh + ((mt * 2 + ks) * 64 + lane) * 8);
                half8 gl = *(const half8*)(GFl + ((mt * 2 + ks) * 64 + lane) * 8);
                Cm = MFMA16(gh, xh[ks], Cm);   // D[dout][x-row]
                Cm = MFMA16(gh, xl[ks], Cm);
                Cm = MFMA16(gl, xh[ks], Cm);
            }
            // C row = dout mt*16+4Q+r, col = x-row c -> slice[x-row][dout]
            *(f32x4*)(slice + c * 68 + mt * 16 + 4 * Q) = Cm;
        }
        __builtin_amdgcn_s_waitcnt(0);   // wave-local LDS RAW
        #pragma unroll
        for (int ks = 0; ks < 2; ks++) {
            const float* qp = slice + c * 68 + ks * 32 + Q * 8;
            const float* up = uW + ks * 32 + Q * 8;
            #pragma unroll
            for (int i = 0; i < 8; i++) {
                float val = qp[i] + up[i];
                _Float16 h = (_Float16)val;
                qh[rt][ks][i] = h;
                ql[rt][ks][i] = (_Float16)(val - (float)h);
            }
        }
        __builtin_amdgcn_s_waitcnt(0);   // reads done before rt=1 overwrites slice
    }

    // ---------------- flash loop: 32 tiles of 32 keys, K dbuf + V in-place prefetch ----------------
    f32x4 acc[2][4];   // [qt][dt] agg^T C-frags (static idx only)
    #pragma unroll
    for (int qt = 0; qt < 2; qt++)
        #pragma unroll
        for (int dt = 0; dt < 4; dt++) acc[qt][dt] = zero4();
    float mrow[2] = { -3.0e38f, -3.0e38f };
    float lrow[2] = { 0.f, 0.f };

    const unsigned short* kfl = KF + lane * 8;   // per-lane frag base (ushort units)
    const unsigned short* vfl = VF + lane * 8;
    half8 kA[4], kB[4], vA[4];
    #pragma unroll
    for (int f = 0; f < 4; f++) kA[f] = *(const half8*)(kfl + f * 512);   // tile 0 K
    #pragma unroll
    for (int d = 0; d < 4; d++) vA[d] = *(const half8*)(vfl + d * 512);   // tile 0 V

    #pragma unroll 1
    for (int TT = 0; TT < 16; TT++) {
        flash_step(kfl, vfl, 2 * TT + 1, kA, kB, vA, qh, ql, acc, mrow, lrow);
        const int Tn = (2 * TT + 2 < 32) ? 2 * TT + 2 : 31;   // clamp last prefetch
        flash_step(kfl, vfl, Tn,         kB, kA, vA, qh, ql, acc, mrow, lrow);
    }

    // ---------------- epilogue: reduce lrow partials, out = (agg/l) @ Wv^T + bv ----------------
    #pragma unroll
    for (int qt = 0; qt < 2; qt++) {
        float l = lrow[qt];
        l += __shfl_xor(l, 16);
        l += __shfl_xor(l, 32);     // once per kernel, not per iter
        const float rl = 1.f / l;
        #pragma unroll
        for (int dt = 0; dt < 4; dt++)
            #pragma unroll
            for (int r = 0; r < 4; r++) acc[qt][dt][r] *= rl;
    }
    half8 wf[4][2];
    #pragma unroll
    for (int mt = 0; mt < 4; mt++)
        #pragma unroll
        for (int ks = 0; ks < 2; ks++) {
            const float* wp = Wv + (size_t)(mt * 16 + c) * 64 + ks * 32 + Q * 8;
            #pragma unroll
            for (int i = 0; i < 8; i++) wf[mt][ks][i] = (_Float16)wp[i];
        }
    const int srcA = 32 * (Q & 1) + c;
    const int srcB = srcA + 16;
    const bool hi = (Q >> 1) & 1;
    f32x4 o[2][4];
    #pragma unroll
    for (int qt = 0; qt < 2; qt++) {
        half8 pe[2];
        #pragma unroll
        for (int ks = 0; ks < 2; ks++) {
            #pragma unroll
            for (int r = 0; r < 4; r++) {
                float a0 = __shfl(acc[qt][2 * ks + 0][r], srcA);
                float a1 = __shfl(acc[qt][2 * ks + 1][r], srcA);
                float b0 = __shfl(acc[qt][2 * ks + 0][r], srcB);
                float b1 = __shfl(acc[qt][2 * ks + 1][r], srcB);
                pe[ks][r]     = (_Float16)(hi ? a1 : a0);
                pe[ks][4 + r] = (_Float16)(hi ? b1 : b0);
            }
        }
        #pragma unroll
        for (int mt = 0; mt < 4; mt++) {
            f32x4 t = MFMA16(wf[mt][0], pe[0], zero4());
            o[qt][mt] = MFMA16(wf[mt][1], pe[1], t);
        }
    }
    float4 bf[4];
    #pragma unroll
    for (int mt = 0; mt < 4; mt++) bf[mt] = *(const float4*)(bv + mt * 16 + 4 * Q);
    #pragma unroll
    for (int qt = 0; qt < 2; qt++) {
        const int row = rbase + qt * 16 + c;
        if (row < N_ROWS) {
            #pragma unroll
            for (int mt = 0; mt < 4; mt++) {
                float4 vv = make_float4(o[qt][mt][0] + bf[mt].x, o[qt][mt][1] + bf[mt].y,
                                        o[qt][mt][2] + bf[mt].z, o[qt][mt][3] + bf[mt].w);
                *(float4*)(out + (size_t)row * 64 + mt * 16 + 4 * Q) = vv;
            }
        }
    }
}

extern "C" void kernel_launch(void* const* d_in, const int* in_sizes, int n_in,
                              void* d_out, int out_size, void* d_ws, size_t ws_size,
                              hipStream_t stream)
{
    const float* x  = (const float*)d_in[0];
    const float* nb = (const float*)d_in[1];
    const float* Wq = (const float*)d_in[2];
    const float* bq = (const float*)d_in[3];
    const float* Wk = (const float*)d_in[4];
    // d_in[5] = bk: provably cancels in softmax -> unused
    const float* Wv = (const float*)d_in[6];
    const float* bv = (const float*)d_in[7];
    float* out = (float*)d_out;

    char* ws = (char*)d_ws;                                  // needs 278784 B
    unsigned short* GFh = (unsigned short*)(ws);             // 8192 B
    unsigned short* GFl = (unsigned short*)(ws + 8192);      // 8192 B
    float*          uW  = (float*)(ws + 16384);              // 256 B
    unsigned short* KF  = (unsigned short*)(ws + 16640);     // 131072 B
    unsigned short* VF  = (unsigned short*)(ws + 147712);    // 131072 B (end 278784)

    prep_kernel<<<17, 256, 0, stream>>>(nb, Wq, bq, Wk, GFh, GFl, uW, KF, VF);
    const int grid = N_ROWS / 32;   // 3125 1-wave blocks, 32 rows each, zero padding
    attn_kernel<<<grid, 64, 0, stream>>>(x, GFh, GFl, uW, KF, VF, Wv, bv, out);
}